// Round 7
// baseline (821.964 us; speedup 1.0000x reference)
//
#include <hip/hip_runtime.h>
#include <hip/hip_bf16.h>
#include <hip/hip_fp16.h>

#define N_NODES 50000
#define N_EDGES 800000

typedef unsigned short ushort_t;
typedef unsigned int uint_t;
typedef __attribute__((ext_vector_type(8))) short short8;
typedef __attribute__((ext_vector_type(4))) float f32x4;

// ---------------- bf16 split helpers ----------------
__device__ inline void split1(float x, ushort_t& h, ushort_t& l) {
    __hip_bfloat16 hb = __float2bfloat16(x);
    float fh = __bfloat162float(hb);
    __hip_bfloat16 lb = __float2bfloat16(x - fh);
    h = __builtin_bit_cast(ushort_t, hb);
    l = __builtin_bit_cast(ushort_t, lb);
}

// ---------------- async global->LDS (16B per lane, wave-uniform LDS base) ----
__device__ inline void gl_lds16(const void* g, void* l) {
    __builtin_amdgcn_global_load_lds(
        (const __attribute__((address_space(1))) unsigned int*)g,
        (__attribute__((address_space(3))) unsigned int*)l, 16, 0, 0);
}

// ---------------- degree count + edge rank ----------------
__global__ void count_deg_k(const int* __restrict__ src, const int* __restrict__ dst,
                            int n_edges, int* __restrict__ deg_out, int* __restrict__ deg_in,
                            int* __restrict__ erank) {
    int i = blockIdx.x * blockDim.x + threadIdx.x;
    if (i < n_edges) {
        atomicAdd(&deg_out[src[i]], 1);
        erank[i] = atomicAdd(&deg_in[dst[i]], 1);
    }
}

// ---------------- norms ----------------
__global__ void norm_k(const int* __restrict__ deg_out, const int* __restrict__ deg_in,
                       float* __restrict__ ns, float* __restrict__ nd, int n) {
    int i = blockIdx.x * blockDim.x + threadIdx.x;
    if (i < n) {
        ns[i] = 1.0f / sqrtf((float)max(deg_out[i], 1));
        nd[i] = 1.0f / sqrtf((float)max(deg_in[i], 1));
    }
}

// ---------------- parallel exclusive scan (3 kernels) ----------------
__global__ void scan_local_k(const int* __restrict__ deg, int* __restrict__ row_start,
                             int* __restrict__ bsum, int n) {
    __shared__ int wexcl[16];
    const int tid = threadIdx.x;
    const int lane = tid & 63, wid = tid >> 6;
    const int i = blockIdx.x * 1024 + tid;
    int v = (i < n) ? deg[i] : 0;
    int x = v;
#pragma unroll
    for (int off = 1; off < 64; off <<= 1) {
        int y = __shfl_up(x, off, 64);
        if (lane >= off) x += y;
    }
    if (lane == 63) wexcl[wid] = x;
    __syncthreads();
    if (wid == 0) {
        int tv = (lane < 16) ? wexcl[lane] : 0;
        int xs = tv;
#pragma unroll
        for (int off = 1; off < 16; off <<= 1) {
            int y = __shfl_up(xs, off, 64);
            if (lane >= off) xs += y;
        }
        if (lane < 16) wexcl[lane] = xs - tv;
    }
    __syncthreads();
    int excl = wexcl[wid] + x - v;
    if (i < n) row_start[i] = excl;
    if (tid == 1023) bsum[blockIdx.x] = excl + v;
}
__global__ void scan_bsum_k(int* __restrict__ bsum, int* __restrict__ total, int nb) {
    int lane = threadIdx.x;
    int v = (lane < nb) ? bsum[lane] : 0;
    int x = v;
#pragma unroll
    for (int off = 1; off < 64; off <<= 1) {
        int y = __shfl_up(x, off, 64);
        if (lane >= off) x += y;
    }
    if (lane < nb) bsum[lane] = x - v;
    if (lane == 63) *total = x;
}
__global__ void scan_add_k(int* __restrict__ row_start, const int* __restrict__ bsum, int n) {
    int i = blockIdx.x * blockDim.x + threadIdx.x;
    if (i < n) row_start[i] += bsum[i >> 10];
}

// ---------------- CSR fill (atomic-free scatter via precomputed rank) --------
__global__ void fill_csr_k(const int* __restrict__ src, const int* __restrict__ dst,
                           int n_edges, const int* __restrict__ row_start,
                           const int* __restrict__ erank, int* __restrict__ edge_src) {
    int i = blockIdx.x * blockDim.x + threadIdx.x;
    if (i < n_edges) {
        edge_src[row_start[dst[i]] + erank[i]] = src[i];
    }
}

// ---------------- split+transpose all 4 weights in one launch ----------------
__global__ void split_weights_k(const float* __restrict__ W0, const float* __restrict__ W1,
                                const float* __restrict__ W2, const float* __restrict__ W3,
                                ushort_t* __restrict__ W0h, ushort_t* __restrict__ W0l,
                                ushort_t* __restrict__ W1h, ushort_t* __restrict__ W1l,
                                ushort_t* __restrict__ W2h, ushort_t* __restrict__ W2l,
                                ushort_t* __restrict__ W3h, ushort_t* __restrict__ W3l) {
    const int s0 = 512 * 256, s1 = s0 + 256 * 256, s2 = s1 + 256 * 128, s3 = s2 + 128 * 64;
    int idx = blockIdx.x * blockDim.x + threadIdx.x;
    const float* W;
    ushort_t *H, *L;
    int K, N, local;
    if (idx < s0) { W = W0; H = W0h; L = W0l; K = 512; N = 256; local = idx; }
    else if (idx < s1) { W = W1; H = W1h; L = W1l; K = 256; N = 256; local = idx - s0; }
    else if (idx < s2) { W = W2; H = W2h; L = W2l; K = 256; N = 128; local = idx - s1; }
    else if (idx < s3) { W = W3; H = W3h; L = W3l; K = 128; N = 64; local = idx - s2; }
    else return;
    int n = local / K;
    int k = local - n * K;
    split1(W[(size_t)k * N + n], H[local], L[local]);
}

// ---------------- MFMA GEMM: C[M,N] = fp16( ns[row] * (A @ W) ), bf16x2 3-pass ----
// (unchanged from round 6: ASRC=0 dbuf DMA pipeline; ASRC=1 single-buf + reg-prefetch)
template <int BN, int ASRC>  // BN: 128 or 64
__global__ __launch_bounds__(256) void gemm_mfma_k(
    const float* __restrict__ Af,
    const ushort_t* __restrict__ Ahi, const ushort_t* __restrict__ Alo,
    const ushort_t* __restrict__ Bhi, const ushort_t* __restrict__ Blo,
    __half* __restrict__ C, int M, int K, int N, const float* __restrict__ ns) {
    constexpr int BM = 128, BK = 32;
    constexpr int WN = (BN == 128) ? 2 : 1;
    constexpr int TM = BM / ((4 / WN) * 16);
    constexpr int TN = BN / (WN * 16);
    constexpr int NBUF = (ASRC == 0) ? 2 : 1;
    __shared__ __attribute__((aligned(16))) ushort_t Ah[NBUF][BM * BK];
    __shared__ __attribute__((aligned(16))) ushort_t Al[NBUF][BM * BK];
    __shared__ __attribute__((aligned(16))) ushort_t Bh[NBUF][BN * BK];
    __shared__ __attribute__((aligned(16))) ushort_t Bl[NBUF][BN * BK];
    const int t = threadIdx.x;
    const int wave = t >> 6, lane = t & 63;
    const int quad = lane >> 4, l16 = lane & 15;
    const int m0 = blockIdx.x * BM, n0 = blockIdx.y * BN;
    const int wrow = (wave / WN) * (TM * 16);
    const int wcol = (wave % WN) * (TN * 16);

    f32x4 acc[TM][TN];
#pragma unroll
    for (int mi = 0; mi < TM; ++mi)
#pragma unroll
        for (int ni = 0; ni < TN; ++ni) acc[mi][ni] = (f32x4){0.f, 0.f, 0.f, 0.f};

    auto stageB = [&](int k0, int buf) {
#pragma unroll
        for (int j = 0; j < BN / 64; ++j) {
            int cg = wave * (BN / 64) + j;
            int c = cg * 64 + lane;
            int r = c >> 2, q = c & 3;
            size_t goff = (size_t)(n0 + r) * K + k0 + q * 8;
            gl_lds16(Bhi + goff, &Bh[buf][cg * 512]);
            gl_lds16(Blo + goff, &Bl[buf][cg * 512]);
        }
    };
    auto stageA_dma = [&](int k0, int buf) {
#pragma unroll
        for (int j = 0; j < 2; ++j) {
            int cg = wave * 2 + j;
            int c = cg * 64 + lane;
            int r = c >> 2, q = c & 3;
            int gr = m0 + r;
            if (gr >= M) gr = M - 1;
            size_t goff = (size_t)gr * K + k0 + q * 8;
            gl_lds16(Ahi + goff, &Ah[buf][cg * 512]);
            gl_lds16(Alo + goff, &Al[buf][cg * 512]);
        }
    };
    float4 pv[2][2];
    auto loadA = [&](int kq) {
#pragma unroll
        for (int j = 0; j < 2; ++j) {
            int c = t + j * 256;
            int r = c >> 2, q = c & 3;
            int gr = m0 + r;
            if (gr >= M) gr = M - 1;
            const float* ap = Af + (size_t)gr * K + kq + q * 8;
            pv[j][0] = *(const float4*)ap;
            pv[j][1] = *(const float4*)(ap + 4);
        }
    };
    auto splitA = [&](int buf) {
#pragma unroll
        for (int j = 0; j < 2; ++j) {
            int c = t + j * 256;
            float vv[8] = {pv[j][0].x, pv[j][0].y, pv[j][0].z, pv[j][0].w,
                           pv[j][1].x, pv[j][1].y, pv[j][1].z, pv[j][1].w};
            short8 hh, ll;
#pragma unroll
            for (int ee = 0; ee < 8; ++ee) {
                ushort_t h, l;
                split1(vv[ee], h, l);
                hh[ee] = (short)h;
                ll[ee] = (short)l;
            }
            *(short8*)&Ah[buf][c * 8] = hh;
            *(short8*)&Al[buf][c * 8] = ll;
        }
    };
    auto compute = [&](int buf) {
        short8 afh[TM], afl[TM], bfh[TN], bfl[TN];
#pragma unroll
        for (int mi = 0; mi < TM; ++mi) {
            int m = wrow + mi * 16 + l16;
            afh[mi] = *(const short8*)&Ah[buf][m * BK + quad * 8];
            afl[mi] = *(const short8*)&Al[buf][m * BK + quad * 8];
        }
#pragma unroll
        for (int ni = 0; ni < TN; ++ni) {
            int n = wcol + ni * 16 + l16;
            bfh[ni] = *(const short8*)&Bh[buf][n * BK + quad * 8];
            bfl[ni] = *(const short8*)&Bl[buf][n * BK + quad * 8];
        }
#pragma unroll
        for (int mi = 0; mi < TM; ++mi)
#pragma unroll
            for (int ni = 0; ni < TN; ++ni) {
                acc[mi][ni] = __builtin_amdgcn_mfma_f32_16x16x32_bf16(afh[mi], bfh[ni],
                                                                      acc[mi][ni], 0, 0, 0);
                acc[mi][ni] = __builtin_amdgcn_mfma_f32_16x16x32_bf16(afh[mi], bfl[ni],
                                                                      acc[mi][ni], 0, 0, 0);
                acc[mi][ni] = __builtin_amdgcn_mfma_f32_16x16x32_bf16(afl[mi], bfh[ni],
                                                                      acc[mi][ni], 0, 0, 0);
            }
    };

    if (ASRC == 0) {
        stageB(0, 0);
        stageA_dma(0, 0);
        __syncthreads();
        int cur = 0;
        for (int k0 = 0; k0 < K; k0 += BK) {
            const int nxt = cur ^ 1;
            if (k0 + BK < K) {
                stageB(k0 + BK, nxt % NBUF);
                stageA_dma(k0 + BK, nxt % NBUF);
            }
            compute(cur);
            __syncthreads();
            cur = nxt % NBUF;
        }
    } else {
        loadA(0);
        for (int k0 = 0; k0 < K; k0 += BK) {
            stageB(k0, 0);
            splitA(0);
            __syncthreads();
            if (k0 + BK < K) loadA(k0 + BK);
            compute(0);
            __syncthreads();
        }
    }
#pragma unroll
    for (int mi = 0; mi < TM; ++mi)
#pragma unroll
        for (int r = 0; r < 4; ++r) {
            int row = m0 + wrow + mi * 16 + quad * 4 + r;
            if (row < M) {
                float s = ns[row];
#pragma unroll
                for (int ni = 0; ni < TN; ++ni) {
                    C[(size_t)row * N + n0 + wcol + ni * 16 + l16] =
                        __float2half(acc[mi][ni][r] * s);
                }
            }
        }
}

// ---------------- slice-partitioned CSR aggregation + fused epilogue ---------
// Each wave = one (node, slice); slice = blockIdx % NSLICES pins all blocks of
// a slice to one XCD (round-robin dispatch), whose 50000x64B = 3.2 MB slice of
// tmp then stays resident in that XCD's 4 MB L2 -> gather runs at L2 speed.
// Wave layout: 4 groups of 16 lanes; group g handles edges == g (mod 4), lane
// k covers 2 cols. Reduce tree (a0+a1)+(a2+a3) matches the old acc[j&3] scheme.
// res = act(nd[w] * sum_{e: dst==w} tmp[src[e]] + bias)
// OUT_MODE: 0 = fp32 only, 1 = hi/lo planes only, 2 = both
template <int NSLICES, int RELU, int OUT_MODE>
__global__ void agg_slice_k(const __half* __restrict__ tmp, float* __restrict__ outF,
                            ushort_t* __restrict__ outH, ushort_t* __restrict__ outL,
                            const int* __restrict__ row_start, const int* __restrict__ edge_src,
                            const float* __restrict__ nd, const float* __restrict__ bias,
                            int n_nodes, int dim) {
    const int wid = threadIdx.x >> 6;
    const int lane = threadIdx.x & 63;
    const int slice = blockIdx.x & (NSLICES - 1);
    const int node = (blockIdx.x / NSLICES) * 4 + wid;
    if (node >= n_nodes) return;
    const int g = lane >> 4, k = lane & 15;
    const int col = slice * 32 + k * 2;
    const __half* base = tmp + col;
    const int s = row_start[node], e = row_start[node + 1];

    float a0 = 0.f, a1 = 0.f;
    int i = s + g;
    // 2-deep MLP within the group (sequential add order preserved)
    for (; i + 4 < e; i += 8) {
        int u0 = edge_src[i];
        int u1 = edge_src[i + 4];
        uint_t w0 = *(const uint_t*)(base + (size_t)u0 * dim);
        uint_t w1 = *(const uint_t*)(base + (size_t)u1 * dim);
        float2 f0 = __half22float2(*reinterpret_cast<__half2*>(&w0));
        float2 f1 = __half22float2(*reinterpret_cast<__half2*>(&w1));
        a0 += f0.x; a1 += f0.y;
        a0 += f1.x; a1 += f1.y;
    }
    for (; i < e; i += 4) {
        int u = edge_src[i];
        uint_t w = *(const uint_t*)(base + (size_t)u * dim);
        float2 f = __half22float2(*reinterpret_cast<__half2*>(&w));
        a0 += f.x; a1 += f.y;
    }
    // cross-group reduce: (a0+a1)+(a2+a3) tree
    a0 += __shfl_xor(a0, 16, 64);
    a1 += __shfl_xor(a1, 16, 64);
    a0 += __shfl_xor(a0, 32, 64);
    a1 += __shfl_xor(a1, 32, 64);
    if (g == 0) {
        float d = nd[node];
        float r0 = fmaf(a0, d, bias[col]);
        float r1 = fmaf(a1, d, bias[col + 1]);
        if (RELU) { r0 = fmaxf(r0, 0.f); r1 = fmaxf(r1, 0.f); }
        size_t ob = (size_t)node * dim + col;
        if (OUT_MODE != 1) {
            *(float2*)(outF + ob) = make_float2(r0, r1);
        }
        if (OUT_MODE != 0) {
            ushort_t h0, l0, h1, l1;
            split1(r0, h0, l0);
            split1(r1, h1, l1);
            *(ushort2*)(outH + ob) = make_ushort2(h0, h1);
            *(ushort2*)(outL + ob) = make_ushort2(l0, l1);
        }
    }
}

extern "C" void kernel_launch(void* const* d_in, const int* in_sizes, int n_in,
                              void* d_out, int out_size, void* d_ws, size_t ws_size,
                              hipStream_t stream) {
    const float* features = (const float*)d_in[0];
    const int* src = (const int*)d_in[1];
    const int* dst = (const int*)d_in[2];
    const float* W0 = (const float*)d_in[3];
    const float* b0 = (const float*)d_in[4];
    const float* W1 = (const float*)d_in[5];
    const float* b1 = (const float*)d_in[6];
    const float* W2 = (const float*)d_in[7];
    const float* b2 = (const float*)d_in[8];
    const float* W3 = (const float*)d_in[9];
    const float* b3 = (const float*)d_in[10];
    float* out = (float*)d_out;

    // workspace carve (~160 MB)
    char* p = (char*)d_ws;
    auto alloc = [&](size_t bytes) {
        void* r = (void*)p;
        p += (bytes + 255) & ~(size_t)255;
        return r;
    };
    __half* tmp = (__half*)alloc((size_t)N_NODES * 256 * 2);        // 25.6 MB GEMM out (fp16)
    ushort_t* H1hi = (ushort_t*)alloc((size_t)N_NODES * 256 * 2);   // [M][256]
    ushort_t* H1lo = (ushort_t*)alloc((size_t)N_NODES * 256 * 2);
    ushort_t* H2hi = (ushort_t*)alloc((size_t)N_NODES * 256 * 2);   // [M][256]
    ushort_t* H2lo = (ushort_t*)alloc((size_t)N_NODES * 256 * 2);
    ushort_t* H3hi = (ushort_t*)alloc((size_t)N_NODES * 128 * 2);   // [M][128]
    ushort_t* H3lo = (ushort_t*)alloc((size_t)N_NODES * 128 * 2);
    ushort_t* W0hi = (ushort_t*)alloc(512 * 256 * 2);               // Wt planes [N][K]
    ushort_t* W0lo = (ushort_t*)alloc(512 * 256 * 2);
    ushort_t* W1hi = (ushort_t*)alloc(256 * 256 * 2);
    ushort_t* W1lo = (ushort_t*)alloc(256 * 256 * 2);
    ushort_t* W2hi = (ushort_t*)alloc(256 * 128 * 2);
    ushort_t* W2lo = (ushort_t*)alloc(256 * 128 * 2);
    ushort_t* W3hi = (ushort_t*)alloc(128 * 64 * 2);
    ushort_t* W3lo = (ushort_t*)alloc(128 * 64 * 2);
    int* edge_src = (int*)alloc((size_t)N_EDGES * 4);
    int* row_start = (int*)alloc((size_t)(N_NODES + 1) * 4);
    int* degO = (int*)alloc((size_t)N_NODES * 4);
    int* degI = (int*)alloc((size_t)N_NODES * 4);
    int* bsum = (int*)alloc(64 * 4);
    float* ns = (float*)alloc((size_t)N_NODES * 4);
    float* nd = (float*)alloc((size_t)N_NODES * 4);
    // erank aliases tmp: only live between count_deg and fill_csr.
    int* erank = (int*)tmp;

    // ---- graph preprocessing ----
    hipMemsetAsync(degO, 0, (size_t)N_NODES * 4, stream);
    hipMemsetAsync(degI, 0, (size_t)N_NODES * 4, stream);
    count_deg_k<<<(N_EDGES + 255) / 256, 256, 0, stream>>>(src, dst, N_EDGES, degO, degI, erank);
    norm_k<<<(N_NODES + 255) / 256, 256, 0, stream>>>(degO, degI, ns, nd, N_NODES);
    {
        const int nb = (N_NODES + 1023) / 1024;  // 49
        scan_local_k<<<nb, 1024, 0, stream>>>(degI, row_start, bsum, N_NODES);
        scan_bsum_k<<<1, 64, 0, stream>>>(bsum, row_start + N_NODES, nb);
        scan_add_k<<<(N_NODES + 255) / 256, 256, 0, stream>>>(row_start, bsum, N_NODES);
    }
    fill_csr_k<<<(N_EDGES + 255) / 256, 256, 0, stream>>>(src, dst, N_EDGES, row_start,
                                                          erank, edge_src);

    // ---- weight splits (one launch) ----
    {
        const int tot = 512 * 256 + 256 * 256 + 256 * 128 + 128 * 64;
        split_weights_k<<<(tot + 255) / 256, 256, 0, stream>>>(
            W0, W1, W2, W3, W0hi, W0lo, W1hi, W1lo, W2hi, W2lo, W3hi, W3lo);
    }

    const int gm = (N_NODES + 127) / 128;       // 391 blocks, BM=128
    const int nodeBlocks = (N_NODES + 3) / 4;   // 12500: 4 nodes (waves) per block

    // ---- layer 0: 512 -> 256 (feature split fused into staging, single-buf) ----
    gemm_mfma_k<128, 1><<<dim3(gm, 2), 256, 0, stream>>>(features, nullptr, nullptr,
                                                         W0hi, W0lo, tmp, N_NODES, 512, 256, ns);
    agg_slice_k<8, 1, 1><<<nodeBlocks * 8, 256, 0, stream>>>(tmp, nullptr, H1hi, H1lo,
                                                             row_start, edge_src, nd, b0,
                                                             N_NODES, 256);

    // ---- layer 1: 256 -> 256 (dbuf DMA pipeline) ----
    gemm_mfma_k<128, 0><<<dim3(gm, 2), 256, 0, stream>>>(nullptr, H1hi, H1lo, W1hi, W1lo,
                                                         tmp, N_NODES, 256, 256, ns);
    agg_slice_k<8, 1, 1><<<nodeBlocks * 8, 256, 0, stream>>>(tmp, nullptr, H2hi, H2lo,
                                                             row_start, edge_src, nd, b1,
                                                             N_NODES, 256);

    // ---- layer 2: 256 -> 128 (aspect_embed -> d_out, planes for L3) ----
    gemm_mfma_k<128, 0><<<dim3(gm, 1), 256, 0, stream>>>(nullptr, H2hi, H2lo, W2hi, W2lo,
                                                         tmp, N_NODES, 256, 128, ns);
    agg_slice_k<4, 0, 2><<<nodeBlocks * 4, 256, 0, stream>>>(tmp, out, H3hi, H3lo,
                                                             row_start, edge_src, nd, b2,
                                                             N_NODES, 128);

    // ---- layer 3: 128 -> 64 (h -> d_out + 50000*128) ----
    gemm_mfma_k<64, 0><<<dim3(gm, 1), 256, 0, stream>>>(nullptr, H3hi, H3lo, W3hi, W3lo,
                                                        tmp, N_NODES, 128, 64, ns);
    agg_slice_k<2, 0, 0><<<nodeBlocks * 2, 256, 0, stream>>>(tmp, out + (size_t)N_NODES * 128,
                                                             nullptr, nullptr, row_start,
                                                             edge_src, nd, b3, N_NODES, 64);
}